// Round 8
// baseline (457.569 us; speedup 1.0000x reference)
//
#include <hip/hip_runtime.h>
#include <hip/hip_fp16.h>
#include <math.h>

// Problem constants
#define CC   512
#define HH   64
#define WW   64
#define HWN  4096      // H*W
#define HEADS 8
#define GROUPS 4
#define HC   64        // C/HEADS
#define CG   128       // C/GROUPS
#define NS   1024      // Hk*Wk = 32*32
#define HK   32
#define SCALE 0.125f   // 64^-0.5
#define RPE_W 127      // 2*H-1
#define RPE_N 16129    // 127*127

typedef _Float16 f16x8 __attribute__((ext_vector_type(8)));
typedef float f32x4 __attribute__((ext_vector_type(4)));

// ---------------------------------------------------------------------------
// fp32 GEMM fallback (verified R4/R6) — used only if ws is too small
// ---------------------------------------------------------------------------
__global__ __launch_bounds__(256) void gemm_bias_kernel(
    const float* __restrict__ A, const float* __restrict__ B,
    const float* __restrict__ bias, float* __restrict__ C,
    int N, int K)
{
  __shared__ __align__(16) float As[32][64];
  __shared__ __align__(16) float Bs[32][64];
  const int bn0 = blockIdx.x * 64;
  const int bm0 = blockIdx.y * 64;
  const int tid = threadIdx.x;
  const int tx = tid & 15, ty = tid >> 4;
  float acc[4][4] = {};

  const int am = tid >> 2;
  const int ak = (tid & 3) * 8;
  const int bn = tid & 63;
  const int bk = (tid >> 6) * 8;

  for (int kt = 0; kt < K; kt += 32) {
    float4 a0 = *(const float4*)&A[(size_t)(bm0 + am) * K + kt + ak];
    float4 a1 = *(const float4*)&A[(size_t)(bm0 + am) * K + kt + ak + 4];
    As[ak + 0][am] = a0.x; As[ak + 1][am] = a0.y;
    As[ak + 2][am] = a0.z; As[ak + 3][am] = a0.w;
    As[ak + 4][am] = a1.x; As[ak + 5][am] = a1.y;
    As[ak + 6][am] = a1.z; As[ak + 7][am] = a1.w;
    #pragma unroll
    for (int r = 0; r < 8; ++r)
      Bs[bk + r][bn] = B[(size_t)(kt + bk + r) * N + bn0 + bn];
    __syncthreads();
    #pragma unroll
    for (int kk = 0; kk < 32; ++kk) {
      float4 a = *(const float4*)&As[kk][ty * 4];
      float4 b = *(const float4*)&Bs[kk][tx * 4];
      acc[0][0] += a.x * b.x; acc[0][1] += a.x * b.y; acc[0][2] += a.x * b.z; acc[0][3] += a.x * b.w;
      acc[1][0] += a.y * b.x; acc[1][1] += a.y * b.y; acc[1][2] += a.y * b.z; acc[1][3] += a.y * b.w;
      acc[2][0] += a.z * b.x; acc[2][1] += a.z * b.y; acc[2][2] += a.z * b.z; acc[2][3] += a.z * b.w;
      acc[3][0] += a.w * b.x; acc[3][1] += a.w * b.y; acc[3][2] += a.w * b.z; acc[3][3] += a.w * b.w;
    }
    __syncthreads();
  }
  #pragma unroll
  for (int i = 0; i < 4; ++i) {
    float bi = bias[bm0 + ty * 4 + i];
    #pragma unroll
    for (int j = 0; j < 4; ++j)
      C[(size_t)(bm0 + ty * 4 + i) * N + bn0 + tx * 4 + j] = acc[i][j] + bi;
  }
}

// ---------------------------------------------------------------------------
// Depthwise 5x5 stride-2 conv (unchanged, verified)
// ---------------------------------------------------------------------------
__global__ __launch_bounds__(256) void dwconv_kernel(
    const float* __restrict__ q, const float* __restrict__ w_dw,
    const float* __restrict__ b_dw, float* __restrict__ t_ws)
{
  __shared__ __align__(16) float plane[HWN];
  const int c = blockIdx.x;
  const int g = blockIdx.y;
  const int tid = threadIdx.x;

  const float* qplane = q + (size_t)(g * CG + c) * HWN;
  for (int i = tid; i < HWN / 4; i += 256)
    ((float4*)plane)[i] = ((const float4*)qplane)[i];

  float wreg[25];
  #pragma unroll
  for (int t = 0; t < 25; ++t) wreg[t] = w_dw[c * 25 + t];
  const float bias = b_dw[c];

  __syncthreads();

  #pragma unroll
  for (int k = 0; k < 4; ++k) {
    int p = (k << 8) | tid;
    int oy = p >> 5, ox = p & 31;
    int iy0 = oy * 2 - 2, ix0 = ox * 2 - 2;
    float acc = bias;
    #pragma unroll
    for (int ky = 0; ky < 5; ++ky) {
      int iy = iy0 + ky;
      bool yok = (iy >= 0) & (iy <= 63);
      int iyc = min(max(iy, 0), 63);
      #pragma unroll
      for (int kx = 0; kx < 5; ++kx) {
        int ix = ix0 + kx;
        bool ok = yok & (ix >= 0) & (ix <= 63);
        int ixc = min(max(ix, 0), 63);
        float v = plane[iyc * 64 + ixc];
        acc += wreg[ky * 5 + kx] * (ok ? v : 0.f);
      }
    }
    t_ws[(size_t)(((g << 10) | p) << 7) + c] = acc;
  }
}

// ---------------------------------------------------------------------------
// LN -> GELU -> 1x1 -> tanh -> pos  (unchanged, verified)
// ---------------------------------------------------------------------------
__device__ __forceinline__ float block_sum_128(float v, float* red, int c) {
  red[c] = v;
  __syncthreads();
  #pragma unroll
  for (int s = 64; s > 0; s >>= 1) {
    if (c < s) red[c] += red[c + s];
    __syncthreads();
  }
  float r = red[0];
  __syncthreads();
  return r;
}

__global__ __launch_bounds__(128) void lnpw_kernel(
    const float* __restrict__ t_ws,
    const float* __restrict__ ln_g, const float* __restrict__ ln_b,
    const float* __restrict__ w_pw,
    float* __restrict__ pos_ws, float* __restrict__ pos_out,
    float* __restrict__ ref_out)
{
  __shared__ float red[128];
  const int blk = blockIdx.x;
  const int g = blk >> 10, p = blk & 1023;
  const int oy = p >> 5, ox = p & 31;
  const int c = threadIdx.x;

  float t = t_ws[(size_t)blk * CG + c];
  float mu = block_sum_128(t, red, c) * (1.f / 128.f);
  float d = t - mu;
  float var = block_sum_128(d * d, red, c) * (1.f / 128.f);
  float u = d * rsqrtf(var + 1e-5f) * ln_g[c] + ln_b[c];
  float ge = 0.5f * u * (1.f + erff(u * 0.70710678118654752f));
  float sy = block_sum_128(w_pw[c] * ge, red, c);
  float sx = block_sum_128(w_pw[128 + c] * ge, red, c);
  if (c == 0) {
    const float scale = 2.0f / 32.0f;
    float offy = tanhf(sy) * scale;
    float offx = tanhf(sx) * scale;
    float refy = ((float)oy + 0.5f) * (2.f / 32.f) - 1.f;
    float refx = ((float)ox + 0.5f) * (2.f / 32.f) - 1.f;
    float py = offy + refy, px = offx + refx;
    int o = (g << 10) | p;
    pos_ws[o * 2 + 0] = py;  pos_ws[o * 2 + 1] = px;
    pos_out[o * 2 + 0] = py; pos_out[o * 2 + 1] = px;
    ref_out[o * 2 + 0] = refy; ref_out[o * 2 + 1] = refx;
  }
}

// ---------------------------------------------------------------------------
// Bilinear sample of x (unchanged, verified)
// ---------------------------------------------------------------------------
__device__ __forceinline__ float tap_img(const float* __restrict__ img,
                                         float xf, float yf, float lim, int Wr) {
  bool v = (xf >= 0.f) & (xf <= lim) & (yf >= 0.f) & (yf <= lim);
  float xc = fminf(fmaxf(xf, 0.f), lim);
  float yc = fminf(fmaxf(yf, 0.f), lim);
  int ix = (int)xc, iy = (int)yc;
  float val = img[iy * Wr + ix];
  return v ? val : 0.f;
}

__global__ __launch_bounds__(256) void sample_kernel(
    const float* __restrict__ x, const float* __restrict__ pos_ws,
    float* __restrict__ xs)
{
  int t = blockIdx.x * 256 + threadIdx.x;
  int c = t >> 10;
  int p = t & 1023;
  int g = c >> 7;
  float py = pos_ws[((g << 10) | p) * 2 + 0];
  float px = pos_ws[((g << 10) | p) * 2 + 1];
  float gx = (px + 1.f) * 0.5f * 63.f;
  float gy = (py + 1.f) * 0.5f * 63.f;
  float x0 = floorf(gx), y0 = floorf(gy);
  float wx = gx - x0, wy = gy - y0;
  const float* img = x + (size_t)c * HWN;
  float v00 = tap_img(img, x0,       y0,       63.f, 64);
  float v01 = tap_img(img, x0 + 1.f, y0,       63.f, 64);
  float v10 = tap_img(img, x0,       y0 + 1.f, 63.f, 64);
  float v11 = tap_img(img, x0 + 1.f, y0 + 1.f, 63.f, 64);
  xs[(size_t)c * NS + p] =
      (v00 * (1.f - wx) + v01 * wx) * (1.f - wy) +
      (v10 * (1.f - wx) + v11 * wx) * wy;
}

// ---------------------------------------------------------------------------
// Split helpers: x = hi(fp16) + lo(fp16), |err| ~ 2^-22 |x|
// ---------------------------------------------------------------------------
__device__ __forceinline__ void split_f16(float x, ushort& h, ushort& l) {
  __half xh = __float2half(x);
  float hf = __half2float(xh);
  __half xl = __float2half(x - hf);
  h = __half_as_ushort(xh);
  l = __half_as_ushort(xl);
}

// Per-head transpose+split (verified R6): src [head*64+ch][ncols] -> [head][col][64]
__global__ __launch_bounds__(256) void tsplit_kernel(
    const float* __restrict__ src, ushort* __restrict__ dh,
    ushort* __restrict__ dl, int ncols)
{
  __shared__ float tile[64][65];
  const int ct = blockIdx.x, hh = blockIdx.y;
  const int tid = threadIdx.x;
  for (int i = tid; i < 4096; i += 256) {
    int ch = i >> 6, m = i & 63;
    tile[ch][m] = src[(size_t)(hh * 64 + ch) * ncols + ct * 64 + m];
  }
  __syncthreads();
  for (int i = tid; i < 4096; i += 256) {
    int m = i >> 6, ch = i & 63;
    ushort h, l;
    split_f16(tile[ch][m], h, l);
    size_t o = ((size_t)hh * ncols + ct * 64 + m) * 64 + ch;
    dh[o] = h; dl[o] = l;
  }
}

// Generalized transpose+split: src [R][N] fp32 -> dst [N][R] fp16 hi/lo
__global__ __launch_bounds__(256) void tsplitg_kernel(
    const float* __restrict__ src, ushort* __restrict__ dh,
    ushort* __restrict__ dl, int R, int N)
{
  __shared__ float tile[64][65];
  const int c0 = blockIdx.x * 64, r0 = blockIdx.y * 64;
  const int tid = threadIdx.x;
  for (int i = tid; i < 4096; i += 256) {
    int rr = i >> 6, cc = i & 63;
    tile[rr][cc] = src[(size_t)(r0 + rr) * N + c0 + cc];
  }
  __syncthreads();
  for (int i = tid; i < 4096; i += 256) {
    int cc = i >> 6, rr = i & 63;
    ushort h, l;
    split_f16(tile[rr][cc], h, l);
    size_t o = (size_t)(c0 + cc) * R + r0 + rr;
    dh[o] = h; dl[o] = l;
  }
}

// Elementwise split (layout preserved)
__global__ __launch_bounds__(256) void vsplit_kernel(
    const float* __restrict__ src, ushort* __restrict__ dh,
    ushort* __restrict__ dl)
{
  int i = blockIdx.x * 256 + threadIdx.x;
  ushort h, l;
  split_f16(src[i], h, l);
  dh[i] = h; dl[i] = l;
}

// ---------------------------------------------------------------------------
// MFMA split-fp16 GEMM: C[m][n] = sum_k A[m][k]*B[n][k] + bias[m]
// A = weight split [M][K]; B = activation transpose-split [N][K].
// Block 256 thr = 4 waves; wave w -> rows bm0+w*16..+15, cols bn0..+63.
// Depth-1 software prefetch (parity double-buffer, statically indexed).
// Fragment conventions identical to the R6-verified attention kernel.
// ---------------------------------------------------------------------------
__global__ __launch_bounds__(256, 2) void mfma_gemm_kernel(
    const ushort* __restrict__ Ah, const ushort* __restrict__ Al,
    const ushort* __restrict__ Bth, const ushort* __restrict__ Btl,
    const float* __restrict__ bias, float* __restrict__ C,
    int N, int K)
{
  const int bn0 = blockIdx.x * 64, bm0 = blockIdx.y * 64;
  const int tid = threadIdx.x, lane = tid & 63;
  const int w = tid >> 6, l15 = lane & 15, lq = lane >> 4;
  const size_t arow = (size_t)(bm0 + w * 16 + l15) * K;
  const int KS = K >> 5;

  f32x4 acc[4];
  #pragma unroll
  for (int nt = 0; nt < 4; ++nt) acc[nt] = (f32x4)0.f;

  f16x8 aHa, aLa, aHb, aLb;
  f16x8 bHa[4], bLa[4], bHb[4], bLb[4];

  // prologue: k-step 0
  aHa = *(const f16x8*)(Ah + arow + lq * 8);
  aLa = *(const f16x8*)(Al + arow + lq * 8);
  #pragma unroll
  for (int nt = 0; nt < 4; ++nt) {
    size_t br = (size_t)(bn0 + nt * 16 + l15) * K + lq * 8;
    bHa[nt] = *(const f16x8*)(Bth + br);
    bLa[nt] = *(const f16x8*)(Btl + br);
  }

  auto bodyG = [&](int ks, f16x8& ach, f16x8& acl, f16x8 (&bch)[4], f16x8 (&bcl)[4],
                   f16x8& anh, f16x8& anl, f16x8 (&bnh)[4], f16x8 (&bnl)[4]) {
    int kn = (ks + 1 < KS) ? ks + 1 : ks;
    int ko = kn * 32 + lq * 8;
    anh = *(const f16x8*)(Ah + arow + ko);
    anl = *(const f16x8*)(Al + arow + ko);
    #pragma unroll
    for (int nt = 0; nt < 4; ++nt) {
      size_t br = (size_t)(bn0 + nt * 16 + l15) * K + ko;
      bnh[nt] = *(const f16x8*)(Bth + br);
      bnl[nt] = *(const f16x8*)(Btl + br);
    }
    #pragma unroll
    for (int nt = 0; nt < 4; ++nt) {
      f32x4 a = acc[nt];
      a = __builtin_amdgcn_mfma_f32_16x16x32_f16(ach, bch[nt], a, 0, 0, 0);
      a = __builtin_amdgcn_mfma_f32_16x16x32_f16(ach, bcl[nt], a, 0, 0, 0);
      a = __builtin_amdgcn_mfma_f32_16x16x32_f16(acl, bch[nt], a, 0, 0, 0);
      acc[nt] = a;
    }
  };

  for (int ks = 0; ks < KS; ks += 2) {
    bodyG(ks,     aHa, aLa, bHa, bLa, aHb, aLb, bHb, bLb);
    bodyG(ks + 1, aHb, aLb, bHb, bLb, aHa, aLa, bHa, bLa);
  }

  float bv[4];
  #pragma unroll
  for (int r = 0; r < 4; ++r) bv[r] = bias[bm0 + w * 16 + lq * 4 + r];
  #pragma unroll
  for (int nt = 0; nt < 4; ++nt)
    #pragma unroll
    for (int r = 0; r < 4; ++r)
      C[(size_t)(bm0 + w * 16 + lq * 4 + r) * N + bn0 + nt * 16 + l15] =
          acc[nt][r] + bv[r];
}

// ---------------------------------------------------------------------------
// MFMA flash attention, software-pipelined (depth-1 K prefetch, pos prefetch,
// V + next-pos issued mid-body).  Fragment/softmax/P/PV structure identical to
// the R6-verified kernel; only scheduling changed.
// ---------------------------------------------------------------------------
__global__ __launch_bounds__(256, 2) void attn_kernel(
    const float*  __restrict__ qb,  // [512][4096] fp32
    const ushort* __restrict__ kth, const ushort* __restrict__ ktl, // [8][1024][64]
    const ushort* __restrict__ vhb, const ushort* __restrict__ vlb, // [512][1024]
    const float* __restrict__ pos,  // [4][1024][2]
    const float* __restrict__ rpe,  // [8][127][127]
    float* __restrict__ ob)         // [512][4096]
{
  __shared__ __align__(16) uint ps32[4][16][64];
  __shared__ float olds[4][64][17];

  const int h = blockIdx.y, m0 = blockIdx.x * 64, g = h >> 1;
  const int tid = threadIdx.x;
  const int w = tid >> 6, lane = tid & 63, l15 = lane & 15, lq = lane >> 4;
  const float* rpeh = rpe + h * RPE_N;

  // Q fragments (in-kernel split, verified R6)
  const int mg = m0 + w * 16 + l15;
  f16x8 qfh[2], qfl[2];
  #pragma unroll
  for (int kst = 0; kst < 2; ++kst) {
    union { f16x8 v; ushort u[8]; } Hh, Ll;
    #pragma unroll
    for (int j = 0; j < 8; ++j) {
      int ch = kst * 32 + lq * 8 + j;
      float qv = qb[((size_t)(h * 64 + ch)) * 4096 + mg];
      ushort hh, ll;
      split_f16(qv, hh, ll);
      Hh.u[j] = hh; Ll.u[j] = ll;
    }
    qfh[kst] = Hh.v; qfl[kst] = Ll.v;
  }

  const float qgy = ((float)(m0 >> 6) + 0.5f) * (2.f / 64.f) - 1.f;
  const float ayp = qgy * 31.5f + 63.f;
  float axp[4];
  #pragma unroll
  for (int r = 0; r < 4; ++r) {
    int ml = w * 16 + lq * 4 + r;
    float qgx = ((float)ml + 0.5f) * (2.f / 64.f) - 1.f;
    axp[r] = qgx * 31.5f + 63.f;
  }

  float mrun[4], lrun[4];
  f32x4 O[4];
  #pragma unroll
  for (int r = 0; r < 4; ++r) { mrun[r] = -INFINITY; lrun[r] = 0.f; }
  #pragma unroll
  for (int t = 0; t < 4; ++t) O[t] = (f32x4)0.f;

  // prefetched pos state (chunk 0)
  float pyv[4], pxv[4];
  #pragma unroll
  for (int nt = 0; nt < 4; ++nt) {
    int n = nt * 16 + l15;
    pyv[nt] = pos[((g << 10) | n) * 2 + 0];
    pxv[nt] = pos[((g << 10) | n) * 2 + 1];
  }

  // K fragment double buffers (chunk 0 -> A)
  f16x8 kAh[4][2], kAl[4][2], kBh[4][2], kBl[4][2];
  #pragma unroll
  for (int nt = 0; nt < 4; ++nt) {
    const ushort* b0 = kth + ((size_t)h * 1024 + nt * 16 + l15) * 64 + lq * 8;
    const ushort* b1 = ktl + ((size_t)h * 1024 + nt * 16 + l15) * 64 + lq * 8;
    kAh[nt][0] = *(const f16x8*)b0;  kAh[nt][1] = *(const f16x8*)(b0 + 32);
    kAl[nt][0] = *(const f16x8*)b1;  kAl[nt][1] = *(const f16x8*)(b1 + 32);
  }

  auto body = [&](int c, f16x8 (&kch)[4][2], f16x8 (&kcl)[4][2],
                  f16x8 (&knh)[4][2], f16x8 (&knl)[4][2]) {
    const int n0c = c * 64;
    const int cn = (c < 15) ? c + 1 : 15;
    const int n0n = cn * 64;

    // (1) issue next-chunk K loads (covered by bias+S below)
    #pragma unroll
    for (int nt = 0; nt < 4; ++nt) {
      const ushort* b0 = kth + ((size_t)h * 1024 + n0n + nt * 16 + l15) * 64 + lq * 8;
      const ushort* b1 = ktl + ((size_t)h * 1024 + n0n + nt * 16 + l15) * 64 + lq * 8;
      knh[nt][0] = *(const f16x8*)b0;  knh[nt][1] = *(const f16x8*)(b0 + 32);
      knl[nt][0] = *(const f16x8*)b1;  knl[nt][1] = *(const f16x8*)(b1 + 32);
    }

    // (2) rpe bias from prefetched pos (gathers issued here)
    float bias[4][4];
    #pragma unroll
    for (int nt = 0; nt < 4; ++nt) {
      float bx = pxv[nt] * 31.5f;
      float gy = ayp - pyv[nt] * 31.5f;
      float y0f = floorf(gy);
      float wy1 = gy - y0f, wy0 = 1.f - wy1;
      bool yv0 = (y0f >= 0.f) & (y0f <= 126.f);
      bool yv1 = (y0f >= -1.f) & (y0f <= 125.f);
      int rr0 = (int)fminf(fmaxf(y0f, 0.f), 126.f) * RPE_W;
      int rr1 = (int)fminf(fmaxf(y0f + 1.f, 0.f), 126.f) * RPE_W;
      #pragma unroll
      for (int r = 0; r < 4; ++r) {
        float gx = axp[r] - bx;
        float x0f = floorf(gx);
        float wx = gx - x0f;
        bool xv0 = (x0f >= 0.f) & (x0f <= 126.f);
        bool xv1 = (x0f >= -1.f) & (x0f <= 125.f);
        int xi0 = (int)fminf(fmaxf(x0f, 0.f), 126.f);
        int xi1 = (int)fminf(fmaxf(x0f + 1.f, 0.f), 126.f);
        float t00 = rpeh[rr0 + xi0];
        float t01 = rpeh[rr0 + xi1];
        float t10 = rpeh[rr1 + xi0];
        float t11 = rpeh[rr1 + xi1];
        float v00 = (xv0 & yv0) ? t00 : 0.f;
        float v01 = (xv1 & yv0) ? t01 : 0.f;
        float v10 = (xv0 & yv1) ? t10 : 0.f;
        float v11 = (xv1 & yv1) ? t11 : 0.f;
        float bt = v00 * (1.f - wx) + v01 * wx;
        float bb = v10 * (1.f - wx) + v11 * wx;
        bias[nt][r] = bt * wy0 + bb * wy1;
      }
    }

    // (3) S = Q K^T  (3-term split)
    f32x4 s[4];
    #pragma unroll
    for (int nt = 0; nt < 4; ++nt) {
      f32x4 acc = (f32x4)0.f;
      acc = __builtin_amdgcn_mfma_f32_16x16x32_f16(qfh[0], kch[nt][0], acc, 0, 0, 0);
      acc = __builtin_amdgcn_mfma_f32_16x16x32_f16(qfh[0], kcl[nt][0], acc, 0, 0, 0);
      acc = __builtin_amdgcn_mfma_f32_16x16x32_f16(qfl[0], kch[nt][0], acc, 0, 0, 0);
      acc = __builtin_amdgcn_mfma_f32_16x16x32_f16(qfh[1], kch[nt][1], acc, 0, 0, 0);
      acc = __builtin_amdgcn_mfma_f32_16x16x32_f16(qfh[1], kcl[nt][1], acc, 0, 0, 0);
      acc = __builtin_amdgcn_mfma_f32_16x16x32_f16(qfl[1], kch[nt][1], acc, 0, 0, 0);
      s[nt] = acc;
    }

    // (4) apply scale+bias
    #pragma unroll
    for (int nt = 0; nt < 4; ++nt)
      #pragma unroll
      for (int r = 0; r < 4; ++r)
        s[nt][r] = s[nt][r] * SCALE + bias[nt][r];

    // (5) issue V loads (current) + pos loads (next) — covered by softmax/P
    f16x8 vfh[4][2], vfl[4][2];
    #pragma unroll
    for (int ct = 0; ct < 4; ++ct) {
      const ushort* b0 = vhb + ((size_t)(h * 64 + ct * 16 + l15)) * 1024 + n0c + lq * 8;
      const ushort* b1 = vlb + ((size_t)(h * 64 + ct * 16 + l15)) * 1024 + n0c + lq * 8;
      vfh[ct][0] = *(const f16x8*)b0;  vfh[ct][1] = *(const f16x8*)(b0 + 32);
      vfl[ct][0] = *(const f16x8*)b1;  vfl[ct][1] = *(const f16x8*)(b1 + 32);
    }
    #pragma unroll
    for (int nt = 0; nt < 4; ++nt) {
      int n = n0n + nt * 16 + l15;
      pyv[nt] = pos[((g << 10) | n) * 2 + 0];
      pxv[nt] = pos[((g << 10) | n) * 2 + 1];
    }

    // (6) online softmax
    #pragma unroll
    for (int r = 0; r < 4; ++r) {
      float rm = fmaxf(fmaxf(s[0][r], s[1][r]), fmaxf(s[2][r], s[3][r]));
      rm = fmaxf(rm, __shfl_xor(rm, 1, 16));
      rm = fmaxf(rm, __shfl_xor(rm, 2, 16));
      rm = fmaxf(rm, __shfl_xor(rm, 4, 16));
      rm = fmaxf(rm, __shfl_xor(rm, 8, 16));
      float mnew = fmaxf(mrun[r], rm);
      float alpha = __expf(mrun[r] - mnew);
      mrun[r] = mnew;
      float rs = 0.f;
      #pragma unroll
      for (int nt = 0; nt < 4; ++nt) {
        float p = __expf(s[nt][r] - mnew);
        s[nt][r] = p;
        rs += p;
      }
      rs += __shfl_xor(rs, 1, 16);
      rs += __shfl_xor(rs, 2, 16);
      rs += __shfl_xor(rs, 4, 16);
      rs += __shfl_xor(rs, 8, 16);
      lrun[r] = lrun[r] * alpha + rs;
      #pragma unroll
      for (int ct = 0; ct < 4; ++ct) O[ct][r] *= alpha;
    }

    // (7) P split -> swizzled per-wave LDS -> A fragments
    #pragma unroll
    for (int nt = 0; nt < 4; ++nt) {
      #pragma unroll
      for (int r = 0; r < 4; ++r) {
        ushort hh, ll;
        split_f16(s[nt][r], hh, ll);
        uint packed = (uint)hh | ((uint)ll << 16);
        int m = lq * 4 + r;
        int n = nt * 16 + l15;
        ps32[w][m][(n & 3) | ((((n >> 2) ^ m) & 15) << 2)] = packed;
      }
    }
    f16x8 pfh[2], pfl[2];
    #pragma unroll
    for (int nst = 0; nst < 2; ++nst) {
      int s0 = nst * 8 + lq * 2;
      uint4 u0 = *(const uint4*)&ps32[w][l15][((s0 ^ l15) & 15) << 2];
      uint4 u1 = *(const uint4*)&ps32[w][l15][(((s0 + 1) ^ l15) & 15) << 2];
      union { f16x8 v; ushort u[8]; } ah, al;
      uint t0[8] = {u0.x, u0.y, u0.z, u0.w, u1.x, u1.y, u1.z, u1.w};
      #pragma unroll
      for (int j = 0; j < 8; ++j) {
        ah.u[j] = (ushort)(t0[j] & 0xffffu);
        al.u[j] = (ushort)(t0[j] >> 16);
      }
      pfh[nst] = ah.v;
      pfl[nst] = al.v;
    }

    // (8) O += P V (3-term split)
    #pragma unroll
    for (int ct = 0; ct < 4; ++ct) {
      f32x4 acc = O[ct];
      acc = __builtin_amdgcn_mfma_f32_16x16x32_f16(pfh[0], vfh[ct][0], acc, 0, 0, 0);
      acc = __builtin_amdgcn_mfma_f32_16x16x32_f16(pfh[0], vfl[ct][0], acc, 0, 0, 0);
      acc = __builtin_amdgcn_mfma_f32_16x16x32_f16(pfl[0], vfh[ct][0], acc, 0, 0, 0);
      acc = __builtin_amdgcn_mfma_f32_16x16x32_f16(pfh[1], vfh[ct][1], acc, 0, 0, 0);
      acc = __builtin_amdgcn_mfma_f32_16x16x32_f16(pfh[1], vfl[ct][1], acc, 0, 0, 0);
      acc = __builtin_amdgcn_mfma_f32_16x16x32_f16(pfl[1], vfh[ct][1], acc, 0, 0, 0);
      O[ct] = acc;
    }
  };

  for (int c = 0; c < 16; c += 2) {
    body(c,     kAh, kAl, kBh, kBl);
    body(c + 1, kBh, kBl, kAh, kAl);
  }

  // normalize + transpose via LDS for coalesced store (wave-internal)
  float inv[4];
  #pragma unroll
  for (int r = 0; r < 4; ++r) inv[r] = 1.f / lrun[r];
  #pragma unroll
  for (int ct = 0; ct < 4; ++ct)
    #pragma unroll
    for (int r = 0; r < 4; ++r)
      olds[w][ct * 16 + l15][lq * 4 + r] = O[ct][r] * inv[r];

  #pragma unroll
  for (int it = 0; it < 16; ++it) {
    int ch = it * 4 + lq;
    ob[((size_t)(h * 64 + ch)) * 4096 + m0 + w * 16 + l15] = olds[w][ch][l15];
  }
}

// ---------------------------------------------------------------------------
extern "C" void kernel_launch(void* const* d_in, const int* in_sizes, int n_in,
                              void* d_out, int out_size, void* d_ws, size_t ws_size,
                              hipStream_t stream) {
  const float* x     = (const float*)d_in[0];
  const float* wq    = (const float*)d_in[1];
  const float* bq    = (const float*)d_in[2];
  const float* wk    = (const float*)d_in[3];
  const float* bk    = (const float*)d_in[4];
  const float* wv    = (const float*)d_in[5];
  const float* bv    = (const float*)d_in[6];
  const float* wo    = (const float*)d_in[7];
  const float* bo    = (const float*)d_in[8];
  const float* w_dw  = (const float*)d_in[9];
  const float* b_dw  = (const float*)d_in[10];
  const float* ln_g  = (const float*)d_in[11];
  const float* ln_b  = (const float*)d_in[12];
  const float* w_pw  = (const float*)d_in[13];
  const float* rpe   = (const float*)d_in[14];

  float* out = (float*)d_out;
  float* y_out   = out;
  float* pos_out = out + 2097152;
  float* ref_out = out + 2097152 + 8192;

  // Base layout (verified footprint)
  float* ws = (float*)d_ws;
  float* qbuf  = ws;                   // 2097152 f (8MB)
  float* posws = qbuf + 2097152;       // 8192 f
  float* xsbuf = posws + 8192;         // 524288 f (t_ws; later kth/ktl)
  float* kbuf  = xsbuf + 524288;       // 524288 f (later vhb/vlb)
  float* vbuf  = kbuf + 524288;        // 524288 f
  float* obuf  = vbuf + 524288;        // 2097152 f (8MB)
  float* t_ws  = xsbuf;
  ushort* kth = (ushort*)xsbuf;        // [8][1024][64]
  ushort* ktl = kth + 524288;
  ushort* vhb = (ushort*)kbuf;         // [512][1024]
  ushort* vlb = vhb + 524288;

  // MFMA-GEMM extension region (weights splits), after obuf
  float* wsp = obuf + 2097152;                  // 1048576 f (4MB)
  const size_t need = (size_t)(6823936) * 4;    // 27.3 MB
  const bool use_mfma_gemm = (ws_size >= need);

  ushort* wqh = (ushort*)wsp;          // each 262144 ushorts
  ushort* wql = wqh + 262144;
  ushort* wkh = wql + 262144;
  ushort* wkl = wkh + 262144;
  ushort* wvh = wkl + 262144;
  ushort* wvl = wvh + 262144;
  ushort* woh = wvl + 262144;
  ushort* wol = woh + 262144;
  // Aliases (stream-ordered, producer/consumer verified):
  ushort* xTh  = (ushort*)obuf;        // [4096][512] (dead after q-gemm)
  ushort* xTl  = xTh + 2097152;
  ushort* xsTh = (ushort*)obuf;        // [1024][512] (dead after k/v gemms)
  ushort* xsTl = xsTh + 524288;
  ushort* oTh  = (ushort*)qbuf;        // [4096][512] (qbuf dead after attn)
  ushort* oTl  = oTh + 2097152;

  if (use_mfma_gemm) {
    // split weights
    vsplit_kernel<<<1024, 256, 0, stream>>>(wq, wqh, wql);
    vsplit_kernel<<<1024, 256, 0, stream>>>(wk, wkh, wkl);
    vsplit_kernel<<<1024, 256, 0, stream>>>(wv, wvh, wvl);
    vsplit_kernel<<<1024, 256, 0, stream>>>(wo, woh, wol);
    // q = wq @ x + bq
    tsplitg_kernel<<<dim3(64, 8), 256, 0, stream>>>(x, xTh, xTl, 512, 4096);
    mfma_gemm_kernel<<<dim3(64, 8), 256, 0, stream>>>(wqh, wql, xTh, xTl, bq, qbuf, 4096, 512);
  } else {
    gemm_bias_kernel<<<dim3(HWN / 64, CC / 64), 256, 0, stream>>>(wq, x, bq, qbuf, HWN, CC);
  }
  // conv_offset
  dwconv_kernel<<<dim3(CG, GROUPS), 256, 0, stream>>>(qbuf, w_dw, b_dw, t_ws);
  lnpw_kernel<<<dim3(GROUPS * NS), 128, 0, stream>>>(t_ws, ln_g, ln_b, w_pw,
                                                     posws, pos_out, ref_out);
  // xs = grid_sample(x, pos)
  sample_kernel<<<dim3(CC * NS / 256), 256, 0, stream>>>(x, posws, xsbuf);
  // k, v projections
  if (use_mfma_gemm) {
    tsplitg_kernel<<<dim3(16, 8), 256, 0, stream>>>(xsbuf, xsTh, xsTl, 512, 1024);
    mfma_gemm_kernel<<<dim3(16, 8), 256, 0, stream>>>(wkh, wkl, xsTh, xsTl, bk, kbuf, 1024, 512);
    mfma_gemm_kernel<<<dim3(16, 8), 256, 0, stream>>>(wvh, wvl, xsTh, xsTl, bv, vbuf, 1024, 512);
  } else {
    gemm_bias_kernel<<<dim3(NS / 64, CC / 64), 256, 0, stream>>>(wk, xsbuf, bk, kbuf, NS, CC);
    gemm_bias_kernel<<<dim3(NS / 64, CC / 64), 256, 0, stream>>>(wv, xsbuf, bv, vbuf, NS, CC);
  }
  // transpose+split K; split V
  tsplit_kernel<<<dim3(NS / 64, HEADS), 256, 0, stream>>>(kbuf, kth, ktl, NS);
  vsplit_kernel<<<dim3(CC * NS / 256), 256, 0, stream>>>(vbuf, vhb, vlb);
  // MFMA flash attention
  attn_kernel<<<dim3(HWN / 64, HEADS), 256, 0, stream>>>(qbuf, kth, ktl,
                                                         vhb, vlb, posws, rpe, obuf);
  // y = wo @ out + bo
  if (use_mfma_gemm) {
    tsplitg_kernel<<<dim3(64, 8), 256, 0, stream>>>(obuf, oTh, oTl, 512, 4096);
    mfma_gemm_kernel<<<dim3(64, 8), 256, 0, stream>>>(woh, wol, oTh, oTl, bo, y_out, 4096, 512);
  } else {
    gemm_bias_kernel<<<dim3(HWN / 64, CC / 64), 256, 0, stream>>>(wo, obuf, bo, y_out, HWN, CC);
  }
}

// Round 9
// 421.803 us; speedup vs baseline: 1.0848x; 1.0848x over previous
//
#include <hip/hip_runtime.h>
#include <hip/hip_fp16.h>
#include <math.h>

// Problem constants
#define CC   512
#define HH   64
#define WW   64
#define HWN  4096      // H*W
#define HEADS 8
#define GROUPS 4
#define HC   64        // C/HEADS
#define CG   128       // C/GROUPS
#define NS   1024      // Hk*Wk = 32*32
#define HK   32
#define SCALE 0.125f   // 64^-0.5
#define RPE_W 127      // 2*H-1
#define RPE_N 16129    // 127*127

typedef _Float16 f16x8 __attribute__((ext_vector_type(8)));
typedef float f32x4 __attribute__((ext_vector_type(4)));

// ---------------------------------------------------------------------------
// fp32 GEMM (verified R4/R6) — all four projections
// ---------------------------------------------------------------------------
__global__ __launch_bounds__(256) void gemm_bias_kernel(
    const float* __restrict__ A, const float* __restrict__ B,
    const float* __restrict__ bias, float* __restrict__ C,
    int N, int K)
{
  __shared__ __align__(16) float As[32][64];
  __shared__ __align__(16) float Bs[32][64];
  const int bn0 = blockIdx.x * 64;
  const int bm0 = blockIdx.y * 64;
  const int tid = threadIdx.x;
  const int tx = tid & 15, ty = tid >> 4;
  float acc[4][4] = {};

  const int am = tid >> 2;
  const int ak = (tid & 3) * 8;
  const int bn = tid & 63;
  const int bk = (tid >> 6) * 8;

  for (int kt = 0; kt < K; kt += 32) {
    float4 a0 = *(const float4*)&A[(size_t)(bm0 + am) * K + kt + ak];
    float4 a1 = *(const float4*)&A[(size_t)(bm0 + am) * K + kt + ak + 4];
    As[ak + 0][am] = a0.x; As[ak + 1][am] = a0.y;
    As[ak + 2][am] = a0.z; As[ak + 3][am] = a0.w;
    As[ak + 4][am] = a1.x; As[ak + 5][am] = a1.y;
    As[ak + 6][am] = a1.z; As[ak + 7][am] = a1.w;
    #pragma unroll
    for (int r = 0; r < 8; ++r)
      Bs[bk + r][bn] = B[(size_t)(kt + bk + r) * N + bn0 + bn];
    __syncthreads();
    #pragma unroll
    for (int kk = 0; kk < 32; ++kk) {
      float4 a = *(const float4*)&As[kk][ty * 4];
      float4 b = *(const float4*)&Bs[kk][tx * 4];
      acc[0][0] += a.x * b.x; acc[0][1] += a.x * b.y; acc[0][2] += a.x * b.z; acc[0][3] += a.x * b.w;
      acc[1][0] += a.y * b.x; acc[1][1] += a.y * b.y; acc[1][2] += a.y * b.z; acc[1][3] += a.y * b.w;
      acc[2][0] += a.z * b.x; acc[2][1] += a.z * b.y; acc[2][2] += a.z * b.z; acc[2][3] += a.z * b.w;
      acc[3][0] += a.w * b.x; acc[3][1] += a.w * b.y; acc[3][2] += a.w * b.z; acc[3][3] += a.w * b.w;
    }
    __syncthreads();
  }
  #pragma unroll
  for (int i = 0; i < 4; ++i) {
    float bi = bias[bm0 + ty * 4 + i];
    #pragma unroll
    for (int j = 0; j < 4; ++j)
      C[(size_t)(bm0 + ty * 4 + i) * N + bn0 + tx * 4 + j] = acc[i][j] + bi;
  }
}

// ---------------------------------------------------------------------------
// Depthwise 5x5 stride-2 conv (unchanged, verified)
// ---------------------------------------------------------------------------
__global__ __launch_bounds__(256) void dwconv_kernel(
    const float* __restrict__ q, const float* __restrict__ w_dw,
    const float* __restrict__ b_dw, float* __restrict__ t_ws)
{
  __shared__ __align__(16) float plane[HWN];
  const int c = blockIdx.x;
  const int g = blockIdx.y;
  const int tid = threadIdx.x;

  const float* qplane = q + (size_t)(g * CG + c) * HWN;
  for (int i = tid; i < HWN / 4; i += 256)
    ((float4*)plane)[i] = ((const float4*)qplane)[i];

  float wreg[25];
  #pragma unroll
  for (int t = 0; t < 25; ++t) wreg[t] = w_dw[c * 25 + t];
  const float bias = b_dw[c];

  __syncthreads();

  #pragma unroll
  for (int k = 0; k < 4; ++k) {
    int p = (k << 8) | tid;
    int oy = p >> 5, ox = p & 31;
    int iy0 = oy * 2 - 2, ix0 = ox * 2 - 2;
    float acc = bias;
    #pragma unroll
    for (int ky = 0; ky < 5; ++ky) {
      int iy = iy0 + ky;
      bool yok = (iy >= 0) & (iy <= 63);
      int iyc = min(max(iy, 0), 63);
      #pragma unroll
      for (int kx = 0; kx < 5; ++kx) {
        int ix = ix0 + kx;
        bool ok = yok & (ix >= 0) & (ix <= 63);
        int ixc = min(max(ix, 0), 63);
        float v = plane[iyc * 64 + ixc];
        acc += wreg[ky * 5 + kx] * (ok ? v : 0.f);
      }
    }
    t_ws[(size_t)(((g << 10) | p) << 7) + c] = acc;
  }
}

// ---------------------------------------------------------------------------
// LN -> GELU -> 1x1 -> tanh -> pos  (unchanged, verified)
// ---------------------------------------------------------------------------
__device__ __forceinline__ float block_sum_128(float v, float* red, int c) {
  red[c] = v;
  __syncthreads();
  #pragma unroll
  for (int s = 64; s > 0; s >>= 1) {
    if (c < s) red[c] += red[c + s];
    __syncthreads();
  }
  float r = red[0];
  __syncthreads();
  return r;
}

__global__ __launch_bounds__(128) void lnpw_kernel(
    const float* __restrict__ t_ws,
    const float* __restrict__ ln_g, const float* __restrict__ ln_b,
    const float* __restrict__ w_pw,
    float* __restrict__ pos_ws, float* __restrict__ pos_out,
    float* __restrict__ ref_out)
{
  __shared__ float red[128];
  const int blk = blockIdx.x;
  const int g = blk >> 10, p = blk & 1023;
  const int oy = p >> 5, ox = p & 31;
  const int c = threadIdx.x;

  float t = t_ws[(size_t)blk * CG + c];
  float mu = block_sum_128(t, red, c) * (1.f / 128.f);
  float d = t - mu;
  float var = block_sum_128(d * d, red, c) * (1.f / 128.f);
  float u = d * rsqrtf(var + 1e-5f) * ln_g[c] + ln_b[c];
  float ge = 0.5f * u * (1.f + erff(u * 0.70710678118654752f));
  float sy = block_sum_128(w_pw[c] * ge, red, c);
  float sx = block_sum_128(w_pw[128 + c] * ge, red, c);
  if (c == 0) {
    const float scale = 2.0f / 32.0f;
    float offy = tanhf(sy) * scale;
    float offx = tanhf(sx) * scale;
    float refy = ((float)oy + 0.5f) * (2.f / 32.f) - 1.f;
    float refx = ((float)ox + 0.5f) * (2.f / 32.f) - 1.f;
    float py = offy + refy, px = offx + refx;
    int o = (g << 10) | p;
    pos_ws[o * 2 + 0] = py;  pos_ws[o * 2 + 1] = px;
    pos_out[o * 2 + 0] = py; pos_out[o * 2 + 1] = px;
    ref_out[o * 2 + 0] = refy; ref_out[o * 2 + 1] = refx;
  }
}

// ---------------------------------------------------------------------------
// Bilinear sample of x (unchanged, verified)
// ---------------------------------------------------------------------------
__device__ __forceinline__ float tap_img(const float* __restrict__ img,
                                         float xf, float yf, float lim, int Wr) {
  bool v = (xf >= 0.f) & (xf <= lim) & (yf >= 0.f) & (yf <= lim);
  float xc = fminf(fmaxf(xf, 0.f), lim);
  float yc = fminf(fmaxf(yf, 0.f), lim);
  int ix = (int)xc, iy = (int)yc;
  float val = img[iy * Wr + ix];
  return v ? val : 0.f;
}

__global__ __launch_bounds__(256) void sample_kernel(
    const float* __restrict__ x, const float* __restrict__ pos_ws,
    float* __restrict__ xs)
{
  int t = blockIdx.x * 256 + threadIdx.x;
  int c = t >> 10;
  int p = t & 1023;
  int g = c >> 7;
  float py = pos_ws[((g << 10) | p) * 2 + 0];
  float px = pos_ws[((g << 10) | p) * 2 + 1];
  float gx = (px + 1.f) * 0.5f * 63.f;
  float gy = (py + 1.f) * 0.5f * 63.f;
  float x0 = floorf(gx), y0 = floorf(gy);
  float wx = gx - x0, wy = gy - y0;
  const float* img = x + (size_t)c * HWN;
  float v00 = tap_img(img, x0,       y0,       63.f, 64);
  float v01 = tap_img(img, x0 + 1.f, y0,       63.f, 64);
  float v10 = tap_img(img, x0,       y0 + 1.f, 63.f, 64);
  float v11 = tap_img(img, x0 + 1.f, y0 + 1.f, 63.f, 64);
  xs[(size_t)c * NS + p] =
      (v00 * (1.f - wx) + v01 * wx) * (1.f - wy) +
      (v10 * (1.f - wx) + v11 * wx) * wy;
}

// ---------------------------------------------------------------------------
// Split helpers: x = hi(fp16) + lo(fp16), |err| ~ 2^-22 |x|
// ---------------------------------------------------------------------------
__device__ __forceinline__ void split_f16(float x, ushort& h, ushort& l) {
  __half xh = __float2half(x);
  float hf = __half2float(xh);
  __half xl = __float2half(x - hf);
  h = __half_as_ushort(xh);
  l = __half_as_ushort(xl);
}

// Per-head transpose+split (verified R6)
__global__ __launch_bounds__(256) void tsplit_kernel(
    const float* __restrict__ src, ushort* __restrict__ dh,
    ushort* __restrict__ dl, int ncols)
{
  __shared__ float tile[64][65];
  const int ct = blockIdx.x, hh = blockIdx.y;
  const int tid = threadIdx.x;
  for (int i = tid; i < 4096; i += 256) {
    int ch = i >> 6, m = i & 63;
    tile[ch][m] = src[(size_t)(hh * 64 + ch) * ncols + ct * 64 + m];
  }
  __syncthreads();
  for (int i = tid; i < 4096; i += 256) {
    int m = i >> 6, ch = i & 63;
    ushort h, l;
    split_f16(tile[ch][m], h, l);
    size_t o = ((size_t)hh * ncols + ct * 64 + m) * 64 + ch;
    dh[o] = h; dl[o] = l;
  }
}

// Elementwise split (layout preserved)
__global__ __launch_bounds__(256) void vsplit_kernel(
    const float* __restrict__ src, ushort* __restrict__ dh,
    ushort* __restrict__ dl)
{
  int i = blockIdx.x * 256 + threadIdx.x;
  ushort h, l;
  split_f16(src[i], h, l);
  dh[i] = h; dl[i] = l;
}

// ---------------------------------------------------------------------------
// MFMA flash attention — EXACT R6-verified body (208 us, no spills),
// parameterized by KV-chunk range (split-KV) and epilogue mode.
//   mode 0: single pass — normalize, write final O.
//   mode 1: split pass — write unnormalized partial O + per-row (m, l).
// blockIdx.z = split index; partial buffers are offset by z inside.
// ---------------------------------------------------------------------------
__global__ __launch_bounds__(256) void attn_kernel(
    const float*  __restrict__ qb,  // [512][4096] fp32
    const ushort* __restrict__ kth, const ushort* __restrict__ ktl, // [8][1024][64]
    const ushort* __restrict__ vhb, const ushort* __restrict__ vlb, // [512][1024]
    const float* __restrict__ pos,  // [4][1024][2]
    const float* __restrict__ rpe,  // [8][127][127]
    float* __restrict__ oO,         // [S][512][4096] (or final [512][4096])
    float* __restrict__ mlm,        // [S][8][4096]
    float* __restrict__ mll,        // [S][8][4096]
    int cps, int mode)              // chunks per split; epilogue mode
{
  __shared__ __align__(16) uint ps32[4][16][64];
  __shared__ float olds[4][64][17];

  const int h = blockIdx.y, m0 = blockIdx.x * 64, g = h >> 1;
  const int sp = blockIdx.z;
  const int c0 = sp * cps, c1 = c0 + cps;
  const int tid = threadIdx.x;
  const int w = tid >> 6, lane = tid & 63, l15 = lane & 15, lq = lane >> 4;
  const float* rpeh = rpe + h * RPE_N;
  float* oOs = oO + (size_t)sp * 2097152;

  // Q fragments (in-kernel split, verified R6)
  const int mg = m0 + w * 16 + l15;
  f16x8 qfh[2], qfl[2];
  #pragma unroll
  for (int kst = 0; kst < 2; ++kst) {
    union { f16x8 v; ushort u[8]; } Hh, Ll;
    #pragma unroll
    for (int j = 0; j < 8; ++j) {
      int ch = kst * 32 + lq * 8 + j;
      float qv = qb[((size_t)(h * 64 + ch)) * 4096 + mg];
      ushort hh, ll;
      split_f16(qv, hh, ll);
      Hh.u[j] = hh; Ll.u[j] = ll;
    }
    qfh[kst] = Hh.v; qfl[kst] = Ll.v;
  }

  const float qgy = ((float)(m0 >> 6) + 0.5f) * (2.f / 64.f) - 1.f;
  const float ayp = qgy * 31.5f + 63.f;
  float axp[4];
  #pragma unroll
  for (int r = 0; r < 4; ++r) {
    int ml = w * 16 + lq * 4 + r;
    float qgx = ((float)ml + 0.5f) * (2.f / 64.f) - 1.f;
    axp[r] = qgx * 31.5f + 63.f;
  }

  float mrun[4], lrun[4];
  f32x4 O[4];
  #pragma unroll
  for (int r = 0; r < 4; ++r) { mrun[r] = -INFINITY; lrun[r] = 0.f; }
  #pragma unroll
  for (int t = 0; t < 4; ++t) O[t] = (f32x4)0.f;

  for (int c = c0; c < c1; ++c) {
    const int n0c = c * 64;

    // K fragments
    f16x8 kfh[4][2], kfl[4][2];
    #pragma unroll
    for (int nt = 0; nt < 4; ++nt) {
      const ushort* b0 = kth + ((size_t)h * 1024 + n0c + nt * 16 + l15) * 64 + lq * 8;
      const ushort* b1 = ktl + ((size_t)h * 1024 + n0c + nt * 16 + l15) * 64 + lq * 8;
      kfh[nt][0] = *(const f16x8*)(b0);  kfh[nt][1] = *(const f16x8*)(b0 + 32);
      kfl[nt][0] = *(const f16x8*)(b1);  kfl[nt][1] = *(const f16x8*)(b1 + 32);
    }

    // S = Q K^T (3-term split)
    f32x4 s[4];
    #pragma unroll
    for (int nt = 0; nt < 4; ++nt) {
      f32x4 acc = (f32x4)0.f;
      acc = __builtin_amdgcn_mfma_f32_16x16x32_f16(qfh[0], kfh[nt][0], acc, 0, 0, 0);
      acc = __builtin_amdgcn_mfma_f32_16x16x32_f16(qfh[0], kfl[nt][0], acc, 0, 0, 0);
      acc = __builtin_amdgcn_mfma_f32_16x16x32_f16(qfl[0], kfh[nt][0], acc, 0, 0, 0);
      acc = __builtin_amdgcn_mfma_f32_16x16x32_f16(qfh[1], kfh[nt][1], acc, 0, 0, 0);
      acc = __builtin_amdgcn_mfma_f32_16x16x32_f16(qfh[1], kfl[nt][1], acc, 0, 0, 0);
      acc = __builtin_amdgcn_mfma_f32_16x16x32_f16(qfl[1], kfh[nt][1], acc, 0, 0, 0);
      s[nt] = acc;
    }

    // V fragments
    f16x8 vfh[4][2], vfl[4][2];
    #pragma unroll
    for (int ct = 0; ct < 4; ++ct) {
      const ushort* b0 = vhb + ((size_t)(h * 64 + ct * 16 + l15)) * 1024 + n0c + lq * 8;
      const ushort* b1 = vlb + ((size_t)(h * 64 + ct * 16 + l15)) * 1024 + n0c + lq * 8;
      vfh[ct][0] = *(const f16x8*)(b0);  vfh[ct][1] = *(const f16x8*)(b0 + 32);
      vfl[ct][0] = *(const f16x8*)(b1);  vfl[ct][1] = *(const f16x8*)(b1 + 32);
    }

    // scale + rpe bias
    #pragma unroll
    for (int nt = 0; nt < 4; ++nt) {
      int n = n0c + nt * 16 + l15;
      float py = pos[((g << 10) | n) * 2 + 0];
      float px = pos[((g << 10) | n) * 2 + 1];
      float bx = px * 31.5f;
      float gy = ayp - py * 31.5f;
      float y0f = floorf(gy);
      float wy1 = gy - y0f, wy0 = 1.f - wy1;
      bool yv0 = (y0f >= 0.f) & (y0f <= 126.f);
      bool yv1 = (y0f >= -1.f) & (y0f <= 125.f);
      int rr0 = (int)fminf(fmaxf(y0f, 0.f), 126.f) * RPE_W;
      int rr1 = (int)fminf(fmaxf(y0f + 1.f, 0.f), 126.f) * RPE_W;
      #pragma unroll
      for (int r = 0; r < 4; ++r) {
        float gx = axp[r] - bx;
        float x0f = floorf(gx);
        float wx = gx - x0f;
        bool xv0 = (x0f >= 0.f) & (x0f <= 126.f);
        bool xv1 = (x0f >= -1.f) & (x0f <= 125.f);
        int xi0 = (int)fminf(fmaxf(x0f, 0.f), 126.f);
        int xi1 = (int)fminf(fmaxf(x0f + 1.f, 0.f), 126.f);
        float t00 = rpeh[rr0 + xi0];
        float t01 = rpeh[rr0 + xi1];
        float t10 = rpeh[rr1 + xi0];
        float t11 = rpeh[rr1 + xi1];
        float v00 = (xv0 & yv0) ? t00 : 0.f;
        float v01 = (xv1 & yv0) ? t01 : 0.f;
        float v10 = (xv0 & yv1) ? t10 : 0.f;
        float v11 = (xv1 & yv1) ? t11 : 0.f;
        float bt = v00 * (1.f - wx) + v01 * wx;
        float bb = v10 * (1.f - wx) + v11 * wx;
        s[nt][r] = s[nt][r] * SCALE + bt * wy0 + bb * wy1;
      }
    }

    // online softmax
    #pragma unroll
    for (int r = 0; r < 4; ++r) {
      float rm = fmaxf(fmaxf(s[0][r], s[1][r]), fmaxf(s[2][r], s[3][r]));
      rm = fmaxf(rm, __shfl_xor(rm, 1, 16));
      rm = fmaxf(rm, __shfl_xor(rm, 2, 16));
      rm = fmaxf(rm, __shfl_xor(rm, 4, 16));
      rm = fmaxf(rm, __shfl_xor(rm, 8, 16));
      float mnew = fmaxf(mrun[r], rm);
      float alpha = __expf(mrun[r] - mnew);
      mrun[r] = mnew;
      float rs = 0.f;
      #pragma unroll
      for (int nt = 0; nt < 4; ++nt) {
        float p = __expf(s[nt][r] - mnew);
        s[nt][r] = p;
        rs += p;
      }
      rs += __shfl_xor(rs, 1, 16);
      rs += __shfl_xor(rs, 2, 16);
      rs += __shfl_xor(rs, 4, 16);
      rs += __shfl_xor(rs, 8, 16);
      lrun[r] = lrun[r] * alpha + rs;
      #pragma unroll
      for (int ct = 0; ct < 4; ++ct) O[ct][r] *= alpha;
    }

    // P split -> swizzled per-wave LDS -> A fragments
    #pragma unroll
    for (int nt = 0; nt < 4; ++nt) {
      #pragma unroll
      for (int r = 0; r < 4; ++r) {
        ushort hh, ll;
        split_f16(s[nt][r], hh, ll);
        uint packed = (uint)hh | ((uint)ll << 16);
        int m = lq * 4 + r;
        int n = nt * 16 + l15;
        ps32[w][m][(n & 3) | ((((n >> 2) ^ m) & 15) << 2)] = packed;
      }
    }
    f16x8 pfh[2], pfl[2];
    #pragma unroll
    for (int nst = 0; nst < 2; ++nst) {
      int s0 = nst * 8 + lq * 2;
      uint4 u0 = *(const uint4*)&ps32[w][l15][((s0 ^ l15) & 15) << 2];
      uint4 u1 = *(const uint4*)&ps32[w][l15][(((s0 + 1) ^ l15) & 15) << 2];
      union { f16x8 v; ushort u[8]; } ah, al;
      uint t0[8] = {u0.x, u0.y, u0.z, u0.w, u1.x, u1.y, u1.z, u1.w};
      #pragma unroll
      for (int j = 0; j < 8; ++j) {
        ah.u[j] = (ushort)(t0[j] & 0xffffu);
        al.u[j] = (ushort)(t0[j] >> 16);
      }
      pfh[nst] = ah.v;
      pfl[nst] = al.v;
    }

    // O += P V (3-term split)
    #pragma unroll
    for (int ct = 0; ct < 4; ++ct) {
      f32x4 acc = O[ct];
      acc = __builtin_amdgcn_mfma_f32_16x16x32_f16(pfh[0], vfh[ct][0], acc, 0, 0, 0);
      acc = __builtin_amdgcn_mfma_f32_16x16x32_f16(pfh[0], vfl[ct][0], acc, 0, 0, 0);
      acc = __builtin_amdgcn_mfma_f32_16x16x32_f16(pfl[0], vfh[ct][0], acc, 0, 0, 0);
      acc = __builtin_amdgcn_mfma_f32_16x16x32_f16(pfh[1], vfh[ct][1], acc, 0, 0, 0);
      acc = __builtin_amdgcn_mfma_f32_16x16x32_f16(pfh[1], vfl[ct][1], acc, 0, 0, 0);
      acc = __builtin_amdgcn_mfma_f32_16x16x32_f16(pfl[1], vfh[ct][1], acc, 0, 0, 0);
      O[ct] = acc;
    }
  }

  // epilogue
  if (mode == 0) {
    float inv[4];
    #pragma unroll
    for (int r = 0; r < 4; ++r) inv[r] = 1.f / lrun[r];
    #pragma unroll
    for (int ct = 0; ct < 4; ++ct)
      #pragma unroll
      for (int r = 0; r < 4; ++r)
        olds[w][ct * 16 + l15][lq * 4 + r] = O[ct][r] * inv[r];
  } else {
    #pragma unroll
    for (int ct = 0; ct < 4; ++ct)
      #pragma unroll
      for (int r = 0; r < 4; ++r)
        olds[w][ct * 16 + l15][lq * 4 + r] = O[ct][r];
    if (l15 == 0) {
      float* mm = mlm + (size_t)sp * 32768 + h * 4096;
      float* ll = mll + (size_t)sp * 32768 + h * 4096;
      #pragma unroll
      for (int r = 0; r < 4; ++r) {
        int row = m0 + w * 16 + lq * 4 + r;
        mm[row] = mrun[r];
        ll[row] = lrun[r];
      }
    }
  }
  #pragma unroll
  for (int it = 0; it < 16; ++it) {
    int ch = it * 4 + lq;
    oOs[((size_t)(h * 64 + ch)) * 4096 + m0 + w * 16 + l15] = olds[w][ch][l15];
  }
}

// ---------------------------------------------------------------------------
// Split-KV combine: O = (O0 e^{m0-M} + O1 e^{m1-M}) / (l0 e^{m0-M} + l1 e^{m1-M})
// In-place into part0 (row layout [512][4096]).  float4 over m.
// ---------------------------------------------------------------------------
__global__ __launch_bounds__(256) void combine_kernel(
    float* __restrict__ part,       // [2][512][4096]
    const float* __restrict__ mlm,  // [2][8][4096]
    const float* __restrict__ mll)  // [2][8][4096]
{
  int idx = blockIdx.x * 256 + threadIdx.x;       // over [512][1024] float4
  int ch = idx >> 10, f4m = idx & 1023;
  int h = ch >> 6;
  float4 p0 = ((const float4*)part)[idx];
  float4 p1 = ((const float4*)(part + 2097152))[idx];
  float4 m0 = *(const float4*)&mlm[h * 4096 + f4m * 4];
  float4 m1 = *(const float4*)&mlm[32768 + h * 4096 + f4m * 4];
  float4 l0 = *(const float4*)&mll[h * 4096 + f4m * 4];
  float4 l1 = *(const float4*)&mll[32768 + h * 4096 + f4m * 4];
  float4 r;
  {
    float M = fmaxf(m0.x, m1.x), e0 = __expf(m0.x - M), e1 = __expf(m1.x - M);
    r.x = (p0.x * e0 + p1.x * e1) / (l0.x * e0 + l1.x * e1);
  }
  {
    float M = fmaxf(m0.y, m1.y), e0 = __expf(m0.y - M), e1 = __expf(m1.y - M);
    r.y = (p0.y * e0 + p1.y * e1) / (l0.y * e0 + l1.y * e1);
  }
  {
    float M = fmaxf(m0.z, m1.z), e0 = __expf(m0.z - M), e1 = __expf(m1.z - M);
    r.z = (p0.z * e0 + p1.z * e1) / (l0.z * e0 + l1.z * e1);
  }
  {
    float M = fmaxf(m0.w, m1.w), e0 = __expf(m0.w - M), e1 = __expf(m1.w - M);
    r.w = (p0.w * e0 + p1.w * e1) / (l0.w * e0 + l1.w * e1);
  }
  ((float4*)part)[idx] = r;
}

// ---------------------------------------------------------------------------
extern "C" void kernel_launch(void* const* d_in, const int* in_sizes, int n_in,
                              void* d_out, int out_size, void* d_ws, size_t ws_size,
                              hipStream_t stream) {
  const float* x     = (const float*)d_in[0];
  const float* wq    = (const float*)d_in[1];
  const float* bq    = (const float*)d_in[2];
  const float* wk    = (const float*)d_in[3];
  const float* bk    = (const float*)d_in[4];
  const float* wv    = (const float*)d_in[5];
  const float* bv    = (const float*)d_in[6];
  const float* wo    = (const float*)d_in[7];
  const float* bo    = (const float*)d_in[8];
  const float* w_dw  = (const float*)d_in[9];
  const float* b_dw  = (const float*)d_in[10];
  const float* ln_g  = (const float*)d_in[11];
  const float* ln_b  = (const float*)d_in[12];
  const float* w_pw  = (const float*)d_in[13];
  const float* rpe   = (const float*)d_in[14];

  float* out = (float*)d_out;
  float* y_out   = out;
  float* pos_out = out + 2097152;
  float* ref_out = out + 2097152 + 8192;

  // Workspace layout
  float* ws = (float*)d_ws;
  float* qbuf  = ws;                   // 2097152 f
  float* posws = qbuf + 2097152;       // 8192 f
  float* xsbuf = posws + 8192;         // 524288 f (t_ws; later kth/ktl)
  float* kbuf  = xsbuf + 524288;       // 524288 f (later vhb/vlb)
  float* vbuf  = kbuf + 524288;        // 524288 f
  float* obuf  = vbuf + 524288;        // 2097152 f  (= split part 0)
  float* part1 = obuf + 2097152;       // 2097152 f  (split part 1)
  float* mlm   = part1 + 2097152;      // 65536 f ([2][8][4096])
  float* mll   = mlm + 65536;          // 65536 f
  float* t_ws  = xsbuf;
  ushort* kth = (ushort*)xsbuf;        // [8][1024][64]
  ushort* ktl = kth + 524288;
  ushort* vhb = (ushort*)kbuf;         // [512][1024]
  ushort* vlb = vhb + 524288;

  const size_t need_split = (size_t)(mll + 65536 - ws) * sizeof(float); // ~32 MB
  const bool use_split = (ws_size >= need_split);

  // q = wq @ x + bq
  gemm_bias_kernel<<<dim3(HWN / 64, CC / 64), 256, 0, stream>>>(wq, x, bq, qbuf, HWN, CC);
  // conv_offset
  dwconv_kernel<<<dim3(CG, GROUPS), 256, 0, stream>>>(qbuf, w_dw, b_dw, t_ws);
  lnpw_kernel<<<dim3(GROUPS * NS), 128, 0, stream>>>(t_ws, ln_g, ln_b, w_pw,
                                                     posws, pos_out, ref_out);
  // xs = grid_sample(x, pos)
  sample_kernel<<<dim3(CC * NS / 256), 256, 0, stream>>>(x, posws, xsbuf);
  // k, v projections
  gemm_bias_kernel<<<dim3(NS / 64, CC / 64), 256, 0, stream>>>(wk, xsbuf, bk, kbuf, NS, CC);
  gemm_bias_kernel<<<dim3(NS / 64, CC / 64), 256, 0, stream>>>(wv, xsbuf, bv, vbuf, NS, CC);
  // transpose+split K; split V
  tsplit_kernel<<<dim3(NS / 64, HEADS), 256, 0, stream>>>(kbuf, kth, ktl, NS);
  vsplit_kernel<<<dim3(CC * NS / 256), 256, 0, stream>>>(vbuf, vhb, vlb);
  // MFMA flash attention
  if (use_split) {
    attn_kernel<<<dim3(HWN / 64, HEADS, 2), 256, 0, stream>>>(
        qbuf, kth, ktl, vhb, vlb, posws, rpe, obuf, mlm, mll, 8, 1);
    combine_kernel<<<2048, 256, 0, stream>>>(obuf, mlm, mll);
  } else {
    attn_kernel<<<dim3(HWN / 64, HEADS, 1), 256, 0, stream>>>(
        qbuf, kth, ktl, vhb, vlb, posws, rpe, obuf, mlm, mll, 16, 0);
  }
  // y = wo @ out + bo
  gemm_bias_kernel<<<dim3(HWN / 64, CC / 64), 256, 0, stream>>>(wo, obuf, bo, y_out, HWN, CC);
}